// Round 3
// baseline (119.889 us; speedup 1.0000x reference)
//
#include <hip/hip_runtime.h>
#include <math.h>

struct F3 { float x, y, z; };

__device__ __forceinline__ F3 f3(float x, float y, float z) { return {x, y, z}; }
__device__ __forceinline__ F3 add(F3 a, F3 b) { return {a.x+b.x, a.y+b.y, a.z+b.z}; }
__device__ __forceinline__ F3 sub(F3 a, F3 b) { return {a.x-b.x, a.y-b.y, a.z-b.z}; }
__device__ __forceinline__ F3 mul(F3 a, float s) { return {a.x*s, a.y*s, a.z*s}; }
__device__ __forceinline__ float dot3(F3 a, F3 b) { return a.x*b.x + a.y*b.y + a.z*b.z; }
__device__ __forceinline__ F3 cross3(F3 a, F3 b) {
    return {a.y*b.z - a.z*b.y, a.z*b.x - a.x*b.z, a.x*b.y - a.y*b.x};
}
__device__ __forceinline__ F3 safe_normalize(F3 a) {
    float d = dot3(a, a);
    float inv = rsqrtf(fmaxf(d, 1e-20f));
    return mul(a, inv);
}

#define BLK 256

// ---------------------------------------------------------------------------
// Kernel 1: per-face geometry -> 3 used float4s per face (stride 4 = 64B/face)
//   tab[4f+0] = {fc.x, fc.y, fc.z, fs}
//   tab[4f+1] = {a0.x, a0.y, a0.z, 0}
//   tab[4f+2] = {a1.x, a1.y, a1.z, 0}
//   a2 is recomputed in the consumer as cross(a0,a1)  (== -normalize(a1 x a0))
// ---------------------------------------------------------------------------
__global__ __launch_bounds__(BLK) void face_precompute_kernel(
    const float* __restrict__ verts, const int* __restrict__ faces,
    float4* __restrict__ tab, int F)
{
    const int f = blockIdx.x * BLK + threadIdx.x;
    if (f >= F) return;
    const int f0 = faces[3*f+0], f1 = faces[3*f+1], f2 = faces[3*f+2];
    const F3 v0 = f3(verts[3*f0], verts[3*f0+1], verts[3*f0+2]);
    const F3 v1 = f3(verts[3*f1], verts[3*f1+1], verts[3*f1+2]);
    const F3 v2 = f3(verts[3*f2], verts[3*f2+1], verts[3*f2+2]);

    const F3 fc  = mul(add(add(v0, v1), v2), (1.0f/3.0f));
    const F3 e01 = sub(v1, v0);
    const F3 e02 = sub(v2, v0);
    const F3 a0 = safe_normalize(e01);
    const F3 a1 = safe_normalize(cross3(a0, e02));
    const F3 a2 = mul(safe_normalize(cross3(a1, a0)), -1.0f);
    const float s0 = sqrtf(dot3(e01, e01));
    const float s1 = fabsf(dot3(a2, e02));
    const float fs = 0.5f * (s0 + s1);

    tab[4*f+0] = make_float4(fc.x, fc.y, fc.z, fs);
    tab[4*f+1] = make_float4(a0.x, a0.y, a0.z, 0.0f);
    tab[4*f+2] = make_float4(a1.x, a1.y, a1.z, 0.0f);
}

// ---------------------------------------------------------------------------
// per-point math (everything in registers; r[] indices static after unroll)
// ---------------------------------------------------------------------------
__device__ __forceinline__ void compute_point(
    float px, float py, float pz,
    float qw, float qx, float qy, float qz,
    float sc0, float sc1, float sc2,
    float opa, float d0, float d1, float d2,
    float4 t0, float4 t1, float4 t2,
    float* __restrict__ r)
{
    const F3 fc = f3(t0.x, t0.y, t0.z);
    const float fs = t0.w;
    const F3 a0 = f3(t1.x, t1.y, t1.z);
    const F3 a1 = f3(t2.x, t2.y, t2.z);
    const F3 a2 = cross3(a0, a1);   // == -normalize(cross(a1,a0)), |a0 x a1| ~ 1

    // xyz_out
    F3 xo = add(add(mul(a0, px), mul(a1, py)), mul(a2, pz));
    xo = add(mul(xo, fs), fc);

    // quaternion -> rotmat
    const float qn = sqrtf(qw*qw + qx*qx + qy*qy + qz*qz) + 1e-12f;
    const float qinv = 1.0f / qn;
    const float w = qw*qinv, x = qx*qinv, y = qy*qinv, z = qz*qinv;
    const float Q00 = 1.0f - 2.0f*(y*y + z*z);
    const float Q01 = 2.0f*(x*y - z*w);
    const float Q02 = 2.0f*(x*z + y*w);
    const float Q10 = 2.0f*(x*y + z*w);
    const float Q11 = 1.0f - 2.0f*(x*x + z*z);
    const float Q12 = 2.0f*(y*z - x*w);
    const float Q20 = 2.0f*(x*z - y*w);
    const float Q21 = 2.0f*(y*z + x*w);
    const float Q22 = 1.0f - 2.0f*(x*x + y*y);

    // M = O*Q columns
    const F3 m0 = add(add(mul(a0, Q00), mul(a1, Q10)), mul(a2, Q20));
    const F3 m1 = add(add(mul(a0, Q01), mul(a1, Q11)), mul(a2, Q21));
    const F3 m2 = add(add(mul(a0, Q02), mul(a1, Q12)), mul(a2, Q22));

    const float w0 = __expf(sc0) * fs;
    const float w1 = __expf(sc1) * fs;
    const float w2 = __expf(sc2) * fs;
    const float t0s = w0*w0, t1s = w1*w1, t2s = w2*w2;

    const float C00 = t0s*m0.x*m0.x + t1s*m1.x*m1.x + t2s*m2.x*m2.x;
    const float C01 = t0s*m0.x*m0.y + t1s*m1.x*m1.y + t2s*m2.x*m2.y;
    const float C02 = t0s*m0.x*m0.z + t1s*m1.x*m1.z + t2s*m2.x*m2.z;
    const float C11 = t0s*m0.y*m0.y + t1s*m1.y*m1.y + t2s*m2.y*m2.y;
    const float C12 = t0s*m0.y*m0.z + t1s*m1.y*m1.z + t2s*m2.y*m2.z;
    const float C22 = t0s*m0.z*m0.z + t1s*m1.z*m1.z + t2s*m2.z*m2.z;

    const float sg = 1.0f / (1.0f + __expf(-opa));
    r[0]  = xo.x; r[1] = xo.y; r[2] = xo.z;
    r[3]  = fminf(fmaxf((0.5f + 0.282f*d0) * 255.0f, 0.0f), 255.0f);
    r[4]  = fminf(fmaxf((0.5f + 0.282f*d1) * 255.0f, 0.0f), 255.0f);
    r[5]  = fminf(fmaxf((0.5f + 0.282f*d2) * 255.0f, 0.0f), 255.0f);
    r[6]  = fminf(fmaxf(sg * 255.0f, 0.0f), 255.0f);
    r[7]  = C00; r[8] = C01; r[9] = C02; r[10] = C11; r[11] = C12; r[12] = C22;
}

// ---------------------------------------------------------------------------
// Kernel 2: 4 points/thread, all streaming I/O as float4
// ---------------------------------------------------------------------------
__global__ __launch_bounds__(BLK) void gauss_main4_kernel(
    const float4* __restrict__ tab,      // (F,4) float4, 3 used
    const int*    __restrict__ binding,  // (N,)
    const float*  __restrict__ xyz,      // (N,3)
    const float*  __restrict__ rot,      // (N,4)
    const float*  __restrict__ scal,     // (N,3)
    const float*  __restrict__ opac,     // (N,1)
    const float*  __restrict__ fdc,      // (N,1,3)
    float*        __restrict__ out,      // (N,13)
    int N)
{
    const int t  = blockIdx.x * BLK + threadIdx.x;
    const int NT = (N + 3) >> 2;
    if (t >= NT) return;
    const int p0 = t * 4;

    if (p0 + 3 < N) {
        // ---- vectorized streaming loads for 4 consecutive points ----
        const int4 b4 = reinterpret_cast<const int4*>(binding)[t];
        float xf[12], sf[12], ff[12], qf[16], of[4];
        #pragma unroll
        for (int j = 0; j < 3; ++j) {
            *reinterpret_cast<float4*>(xf + 4*j) = reinterpret_cast<const float4*>(xyz )[3*t + j];
            *reinterpret_cast<float4*>(sf + 4*j) = reinterpret_cast<const float4*>(scal)[3*t + j];
            *reinterpret_cast<float4*>(ff + 4*j) = reinterpret_cast<const float4*>(fdc )[3*t + j];
        }
        #pragma unroll
        for (int j = 0; j < 4; ++j)
            *reinterpret_cast<float4*>(qf + 4*j) = reinterpret_cast<const float4*>(rot)[4*t + j];
        *reinterpret_cast<float4*>(of) = reinterpret_cast<const float4*>(opac)[t];

        const int bs[4] = {b4.x, b4.y, b4.z, b4.w};
        float res[52];
        #pragma unroll
        for (int p = 0; p < 4; ++p) {
            const float4 t0 = tab[4*bs[p] + 0];
            const float4 t1 = tab[4*bs[p] + 1];
            const float4 t2 = tab[4*bs[p] + 2];
            compute_point(xf[3*p], xf[3*p+1], xf[3*p+2],
                          qf[4*p], qf[4*p+1], qf[4*p+2], qf[4*p+3],
                          sf[3*p], sf[3*p+1], sf[3*p+2],
                          of[p], ff[3*p], ff[3*p+1], ff[3*p+2],
                          t0, t1, t2, res + 13*p);
        }

        // ---- 13 aligned float4 stores (52 contiguous floats per thread) ----
        float4* o4 = reinterpret_cast<float4*>(out + (size_t)t * 52);
        #pragma unroll
        for (int j = 0; j < 13; ++j)
            o4[j] = make_float4(res[4*j], res[4*j+1], res[4*j+2], res[4*j+3]);
    } else {
        // ---- generic tail (unused when N % 4 == 0) ----
        for (int i = p0; i < N; ++i) {
            const int b = binding[i];
            const float4 t0 = tab[4*b + 0];
            const float4 t1 = tab[4*b + 1];
            const float4 t2 = tab[4*b + 2];
            float r[13];
            compute_point(xyz[3*i], xyz[3*i+1], xyz[3*i+2],
                          rot[4*i], rot[4*i+1], rot[4*i+2], rot[4*i+3],
                          scal[3*i], scal[3*i+1], scal[3*i+2],
                          opac[i], fdc[3*i], fdc[3*i+1], fdc[3*i+2],
                          t0, t1, t2, r);
            #pragma unroll
            for (int j = 0; j < 13; ++j) out[(size_t)i*13 + j] = r[j];
        }
    }
}

// ---------------------------------------------------------------------------
// Fallback: fully fused single kernel (only if ws_size too small)
// ---------------------------------------------------------------------------
__global__ __launch_bounds__(BLK) void gauss_fused_kernel(
    const float* __restrict__ verts, const int* __restrict__ faces,
    const int* __restrict__ binding, const float* __restrict__ xyz,
    const float* __restrict__ rot, const float* __restrict__ scal,
    const float* __restrict__ opac, const float* __restrict__ fdc,
    float* __restrict__ out, int N)
{
    const int i = blockIdx.x * BLK + threadIdx.x;
    if (i >= N) return;
    const int b = binding[i];
    const int f0 = faces[3*b+0], f1 = faces[3*b+1], f2 = faces[3*b+2];
    const F3 v0 = f3(verts[3*f0], verts[3*f0+1], verts[3*f0+2]);
    const F3 v1 = f3(verts[3*f1], verts[3*f1+1], verts[3*f1+2]);
    const F3 v2 = f3(verts[3*f2], verts[3*f2+1], verts[3*f2+2]);
    const F3 fc  = mul(add(add(v0, v1), v2), (1.0f/3.0f));
    const F3 e01 = sub(v1, v0);
    const F3 e02 = sub(v2, v0);
    const F3 a0 = safe_normalize(e01);
    const F3 a1 = safe_normalize(cross3(a0, e02));
    const float s0 = sqrtf(dot3(e01, e01));
    const F3 a2r = mul(safe_normalize(cross3(a1, a0)), -1.0f);
    const float s1 = fabsf(dot3(a2r, e02));
    const float fs = 0.5f * (s0 + s1);
    float r[13];
    compute_point(xyz[3*i], xyz[3*i+1], xyz[3*i+2],
                  rot[4*i], rot[4*i+1], rot[4*i+2], rot[4*i+3],
                  scal[3*i], scal[3*i+1], scal[3*i+2],
                  opac[i], fdc[3*i], fdc[3*i+1], fdc[3*i+2],
                  make_float4(fc.x, fc.y, fc.z, fs),
                  make_float4(a0.x, a0.y, a0.z, 0.0f),
                  make_float4(a1.x, a1.y, a1.z, 0.0f), r);
    #pragma unroll
    for (int j = 0; j < 13; ++j) out[(size_t)i*13 + j] = r[j];
}

extern "C" void kernel_launch(void* const* d_in, const int* in_sizes, int n_in,
                              void* d_out, int out_size, void* d_ws, size_t ws_size,
                              hipStream_t stream) {
    const float* verts   = (const float*)d_in[0];
    const int*   faces   = (const int*)  d_in[1];
    const int*   binding = (const int*)  d_in[2];
    const float* xyz     = (const float*)d_in[3];
    const float* rot     = (const float*)d_in[4];
    const float* scal    = (const float*)d_in[5];
    const float* opac    = (const float*)d_in[6];
    const float* fdc     = (const float*)d_in[7];
    // d_in[8] = features_rest: unused by the reference output
    float* out = (float*)d_out;
    const int N = in_sizes[2];
    const int F = in_sizes[1] / 3;

    const size_t tab_bytes = (size_t)F * 4 * sizeof(float4);

    if (ws_size >= tab_bytes) {
        float4* tab = (float4*)d_ws;
        const int fblocks = (F + BLK - 1) / BLK;
        face_precompute_kernel<<<fblocks, BLK, 0, stream>>>(verts, faces, tab, F);
        const int NT = (N + 3) / 4;
        const int blocks = (NT + BLK - 1) / BLK;
        gauss_main4_kernel<<<blocks, BLK, 0, stream>>>(
            tab, binding, xyz, rot, scal, opac, fdc, out, N);
    } else {
        const int blocks = (N + BLK - 1) / BLK;
        gauss_fused_kernel<<<blocks, BLK, 0, stream>>>(
            verts, faces, binding, xyz, rot, scal, opac, fdc, out, N);
    }
}

// Round 4
// 45.692 us; speedup vs baseline: 2.6239x; 2.6239x over previous
//
#include <hip/hip_runtime.h>
#include <math.h>

struct F3 { float x, y, z; };

__device__ __forceinline__ F3 f3(float x, float y, float z) { return {x, y, z}; }
__device__ __forceinline__ F3 add(F3 a, F3 b) { return {a.x+b.x, a.y+b.y, a.z+b.z}; }
__device__ __forceinline__ F3 sub(F3 a, F3 b) { return {a.x-b.x, a.y-b.y, a.z-b.z}; }
__device__ __forceinline__ F3 mul(F3 a, float s) { return {a.x*s, a.y*s, a.z*s}; }
__device__ __forceinline__ float dot3(F3 a, F3 b) { return a.x*b.x + a.y*b.y + a.z*b.z; }
__device__ __forceinline__ F3 cross3(F3 a, F3 b) {
    return {a.y*b.z - a.z*b.y, a.z*b.x - a.x*b.z, a.x*b.y - a.y*b.x};
}
__device__ __forceinline__ F3 safe_normalize(F3 a) {
    float d = dot3(a, a);
    float inv = rsqrtf(fmaxf(d, 1e-20f));
    return mul(a, inv);
}

#define BLK 256

// ---------------------------------------------------------------------------
// Kernel 1: per-face geometry -> 3 float4 per face, stride 4 (64B record)
//   tab[4f+0] = {fc.x, fc.y, fc.z, fs}
//   tab[4f+1] = {a0.x, a0.y, a0.z, 0}
//   tab[4f+2] = {a1.x, a1.y, a1.z, 0}
//   consumer recomputes a2 = cross(a0, a1)  (== -normalize(cross(a1,a0)))
// ---------------------------------------------------------------------------
__global__ __launch_bounds__(BLK) void face_precompute_kernel(
    const float* __restrict__ verts, const int* __restrict__ faces,
    float4* __restrict__ tab, int F)
{
    const int f = blockIdx.x * BLK + threadIdx.x;
    if (f >= F) return;
    const int f0 = faces[3*f+0], f1 = faces[3*f+1], f2 = faces[3*f+2];
    const F3 v0 = f3(verts[3*f0], verts[3*f0+1], verts[3*f0+2]);
    const F3 v1 = f3(verts[3*f1], verts[3*f1+1], verts[3*f1+2]);
    const F3 v2 = f3(verts[3*f2], verts[3*f2+1], verts[3*f2+2]);

    const F3 fc  = mul(add(add(v0, v1), v2), (1.0f/3.0f));
    const F3 e01 = sub(v1, v0);
    const F3 e02 = sub(v2, v0);
    const F3 a0 = safe_normalize(e01);
    const F3 a1 = safe_normalize(cross3(a0, e02));
    const F3 a2 = mul(safe_normalize(cross3(a1, a0)), -1.0f);
    const float s0 = sqrtf(dot3(e01, e01));
    const float s1 = fabsf(dot3(a2, e02));
    const float fs = 0.5f * (s0 + s1);

    tab[4*f+0] = make_float4(fc.x, fc.y, fc.z, fs);
    tab[4*f+1] = make_float4(a0.x, a0.y, a0.z, 0.0f);
    tab[4*f+2] = make_float4(a1.x, a1.y, a1.z, 0.0f);
}

// ---------------------------------------------------------------------------
// per-point math: all named scalars in/out (struct return -> SROA-friendly)
// ---------------------------------------------------------------------------
struct Out13 {
    float x0, x1, x2;          // xyz_out
    float c0, c1, c2, c3;      // color
    float s0, s1, s2, s3, s4, s5;  // sigma packed
};

__device__ __forceinline__ Out13 compute_point(
    float px, float py, float pz,
    float qw, float qx, float qy, float qz,
    float sc0, float sc1, float sc2,
    float opa, float d0, float d1, float d2,
    float4 t0, float4 t1, float4 t2)
{
    const F3 fc = f3(t0.x, t0.y, t0.z);
    const float fs = t0.w;
    const F3 a0 = f3(t1.x, t1.y, t1.z);
    const F3 a1 = f3(t2.x, t2.y, t2.z);
    const F3 a2 = cross3(a0, a1);   // unit, == reference a2 up to ~1e-7

    F3 xo = add(add(mul(a0, px), mul(a1, py)), mul(a2, pz));
    xo = add(mul(xo, fs), fc);

    const float qn = sqrtf(qw*qw + qx*qx + qy*qy + qz*qz) + 1e-12f;
    const float qinv = 1.0f / qn;
    const float w = qw*qinv, x = qx*qinv, y = qy*qinv, z = qz*qinv;
    const float Q00 = 1.0f - 2.0f*(y*y + z*z);
    const float Q01 = 2.0f*(x*y - z*w);
    const float Q02 = 2.0f*(x*z + y*w);
    const float Q10 = 2.0f*(x*y + z*w);
    const float Q11 = 1.0f - 2.0f*(x*x + z*z);
    const float Q12 = 2.0f*(y*z - x*w);
    const float Q20 = 2.0f*(x*z - y*w);
    const float Q21 = 2.0f*(y*z + x*w);
    const float Q22 = 1.0f - 2.0f*(x*x + y*y);

    const F3 m0 = add(add(mul(a0, Q00), mul(a1, Q10)), mul(a2, Q20));
    const F3 m1 = add(add(mul(a0, Q01), mul(a1, Q11)), mul(a2, Q21));
    const F3 m2 = add(add(mul(a0, Q02), mul(a1, Q12)), mul(a2, Q22));

    const float w0 = __expf(sc0) * fs;
    const float w1 = __expf(sc1) * fs;
    const float w2 = __expf(sc2) * fs;
    const float t0s = w0*w0, t1s = w1*w1, t2s = w2*w2;

    Out13 o;
    o.s0 = t0s*m0.x*m0.x + t1s*m1.x*m1.x + t2s*m2.x*m2.x;
    o.s1 = t0s*m0.x*m0.y + t1s*m1.x*m1.y + t2s*m2.x*m2.y;
    o.s2 = t0s*m0.x*m0.z + t1s*m1.x*m1.z + t2s*m2.x*m2.z;
    o.s3 = t0s*m0.y*m0.y + t1s*m1.y*m1.y + t2s*m2.y*m2.y;
    o.s4 = t0s*m0.y*m0.z + t1s*m1.y*m1.z + t2s*m2.y*m2.z;
    o.s5 = t0s*m0.z*m0.z + t1s*m1.z*m1.z + t2s*m2.z*m2.z;

    const float sg = 1.0f / (1.0f + __expf(-opa));
    o.x0 = xo.x; o.x1 = xo.y; o.x2 = xo.z;
    o.c0 = fminf(fmaxf((0.5f + 0.282f*d0) * 255.0f, 0.0f), 255.0f);
    o.c1 = fminf(fmaxf((0.5f + 0.282f*d1) * 255.0f, 0.0f), 255.0f);
    o.c2 = fminf(fmaxf((0.5f + 0.282f*d2) * 255.0f, 0.0f), 255.0f);
    o.c3 = fminf(fmaxf(sg * 255.0f, 0.0f), 255.0f);
    return o;
}

// ---------------------------------------------------------------------------
// Kernel 2: 1 point/thread; stride-3 streams staged via LDS as float4;
// output staged via LDS, flushed as coalesced float4
// ---------------------------------------------------------------------------
__global__ __launch_bounds__(BLK) void gauss_main_kernel(
    const float4* __restrict__ tab,      // (F,4) float4, 3 used
    const int*    __restrict__ binding,  // (N,)
    const float*  __restrict__ xyz,      // (N,3)
    const float*  __restrict__ rot,      // (N,4)
    const float*  __restrict__ scal,     // (N,3)
    const float*  __restrict__ opac,     // (N,1)
    const float*  __restrict__ fdc,      // (N,1,3)
    float*        __restrict__ out,      // (N,13)
    int N)
{
    __shared__ float sin_[3 * BLK * 3];   // [xyz | scal | fdc], 768 floats each
    __shared__ float sout[BLK * 13];

    const int tid  = threadIdx.x;
    const int base = blockIdx.x * BLK;
    const int i    = base + tid;
    const int count = min(BLK, N - base);
    const bool full = (count == BLK);

    // issue the gather-chain root as early as possible
    const int b = (i < N) ? binding[i] : 0;

    if (full) {
        // cooperative vectorized staging of the three stride-3 streams
        const float4* x4 = reinterpret_cast<const float4*>(xyz  + (size_t)base * 3);
        const float4* s4 = reinterpret_cast<const float4*>(scal + (size_t)base * 3);
        const float4* f4 = reinterpret_cast<const float4*>(fdc  + (size_t)base * 3);
        float4* sv = reinterpret_cast<float4*>(sin_);
        if (tid < 192) {               // 192 float4 per array
            sv[      tid] = x4[tid];
            sv[192 + tid] = s4[tid];
            sv[384 + tid] = f4[tid];
        }
    }

    // per-point coalesced / gathered loads (independent of LDS staging)
    float4 q4 = make_float4(0,0,0,1);
    float opa = 0.0f;
    float4 t0 = make_float4(0,0,0,0), t1 = t0, t2 = t0;
    if (i < N) {
        q4  = reinterpret_cast<const float4*>(rot)[i];
        opa = opac[i];
        t0  = tab[4*b+0];
        t1  = tab[4*b+1];
        t2  = tab[4*b+2];
    }

    float px, py, pz, sc0, sc1, sc2, d0, d1, d2;
    if (full) {
        __syncthreads();
        px  = sin_[        3*tid    ]; py  = sin_[        3*tid + 1]; pz  = sin_[        3*tid + 2];
        sc0 = sin_[ 768 +  3*tid    ]; sc1 = sin_[ 768 +  3*tid + 1]; sc2 = sin_[ 768 +  3*tid + 2];
        d0  = sin_[1536 +  3*tid    ]; d1  = sin_[1536 +  3*tid + 1]; d2  = sin_[1536 +  3*tid + 2];
    } else {
        px = py = pz = sc0 = sc1 = sc2 = d0 = d1 = d2 = 0.0f;
        if (i < N) {
            px  = xyz [3*i]; py  = xyz [3*i+1]; pz  = xyz [3*i+2];
            sc0 = scal[3*i]; sc1 = scal[3*i+1]; sc2 = scal[3*i+2];
            d0  = fdc [3*i]; d1  = fdc [3*i+1]; d2  = fdc [3*i+2];
        }
    }

    if (i < N) {
        const Out13 o = compute_point(px, py, pz,
                                      q4.x, q4.y, q4.z, q4.w,
                                      sc0, sc1, sc2, opa, d0, d1, d2,
                                      t0, t1, t2);
        float* s = sout + tid * 13;
        s[0] = o.x0; s[1] = o.x1; s[2]  = o.x2;
        s[3] = o.c0; s[4] = o.c1; s[5]  = o.c2; s[6] = o.c3;
        s[7] = o.s0; s[8] = o.s1; s[9]  = o.s2;
        s[10] = o.s3; s[11] = o.s4; s[12] = o.s5;
    }

    __syncthreads();

    // coalesced float4 flush of the block's contiguous output span
    const int total = count * 13;
    const size_t obase = (size_t)base * 13;
    const int n4 = total >> 2;
    const float4* sf = reinterpret_cast<const float4*>(sout);
    float4* o4 = reinterpret_cast<float4*>(out + obase);
    for (int j = tid; j < n4; j += BLK) o4[j] = sf[j];
    for (int j = (n4 << 2) + tid; j < total; j += BLK) out[obase + j] = sout[j];
}

// ---------------------------------------------------------------------------
// Fallback: fully fused single kernel (only if ws_size too small)
// ---------------------------------------------------------------------------
__global__ __launch_bounds__(BLK) void gauss_fused_kernel(
    const float* __restrict__ verts, const int* __restrict__ faces,
    const int* __restrict__ binding, const float* __restrict__ xyz,
    const float* __restrict__ rot, const float* __restrict__ scal,
    const float* __restrict__ opac, const float* __restrict__ fdc,
    float* __restrict__ out, int N)
{
    const int i = blockIdx.x * BLK + threadIdx.x;
    if (i >= N) return;
    const int b = binding[i];
    const int f0 = faces[3*b+0], f1 = faces[3*b+1], f2 = faces[3*b+2];
    const F3 v0 = f3(verts[3*f0], verts[3*f0+1], verts[3*f0+2]);
    const F3 v1 = f3(verts[3*f1], verts[3*f1+1], verts[3*f1+2]);
    const F3 v2 = f3(verts[3*f2], verts[3*f2+1], verts[3*f2+2]);
    const F3 fc  = mul(add(add(v0, v1), v2), (1.0f/3.0f));
    const F3 e01 = sub(v1, v0);
    const F3 e02 = sub(v2, v0);
    const F3 a0 = safe_normalize(e01);
    const F3 a1 = safe_normalize(cross3(a0, e02));
    const float s0 = sqrtf(dot3(e01, e01));
    const F3 a2r = mul(safe_normalize(cross3(a1, a0)), -1.0f);
    const float s1 = fabsf(dot3(a2r, e02));
    const float fs = 0.5f * (s0 + s1);

    const Out13 o = compute_point(xyz[3*i], xyz[3*i+1], xyz[3*i+2],
                                  rot[4*i], rot[4*i+1], rot[4*i+2], rot[4*i+3],
                                  scal[3*i], scal[3*i+1], scal[3*i+2],
                                  opac[i], fdc[3*i], fdc[3*i+1], fdc[3*i+2],
                                  make_float4(fc.x, fc.y, fc.z, fs),
                                  make_float4(a0.x, a0.y, a0.z, 0.0f),
                                  make_float4(a1.x, a1.y, a1.z, 0.0f));
    float* op = out + (size_t)i * 13;
    op[0] = o.x0; op[1] = o.x1; op[2]  = o.x2;
    op[3] = o.c0; op[4] = o.c1; op[5]  = o.c2; op[6] = o.c3;
    op[7] = o.s0; op[8] = o.s1; op[9]  = o.s2;
    op[10] = o.s3; op[11] = o.s4; op[12] = o.s5;
}

extern "C" void kernel_launch(void* const* d_in, const int* in_sizes, int n_in,
                              void* d_out, int out_size, void* d_ws, size_t ws_size,
                              hipStream_t stream) {
    const float* verts   = (const float*)d_in[0];
    const int*   faces   = (const int*)  d_in[1];
    const int*   binding = (const int*)  d_in[2];
    const float* xyz     = (const float*)d_in[3];
    const float* rot     = (const float*)d_in[4];
    const float* scal    = (const float*)d_in[5];
    const float* opac    = (const float*)d_in[6];
    const float* fdc     = (const float*)d_in[7];
    // d_in[8] = features_rest: unused by the reference output
    float* out = (float*)d_out;
    const int N = in_sizes[2];
    const int F = in_sizes[1] / 3;

    const size_t tab_bytes = (size_t)F * 4 * sizeof(float4);
    const int blocks = (N + BLK - 1) / BLK;

    if (ws_size >= tab_bytes) {
        float4* tab = (float4*)d_ws;
        const int fblocks = (F + BLK - 1) / BLK;
        face_precompute_kernel<<<fblocks, BLK, 0, stream>>>(verts, faces, tab, F);
        gauss_main_kernel<<<blocks, BLK, 0, stream>>>(
            tab, binding, xyz, rot, scal, opac, fdc, out, N);
    } else {
        gauss_fused_kernel<<<blocks, BLK, 0, stream>>>(
            verts, faces, binding, xyz, rot, scal, opac, fdc, out, N);
    }
}